// Round 1
// baseline (3838.337 us; speedup 1.0000x reference)
//
#include <hip/hip_runtime.h>
#include <math.h>

#define CIN  32
#define COUT 64
#define KVOL 27
#define EPSF 1e-5f

__device__ __forceinline__ float eluf(float x) { return x > 0.f ? x : expm1f(x); }

// monotone float<->uint encoding for atomicMax-based segment max
__device__ __forceinline__ unsigned encf(float x) {
    unsigned b = __float_as_uint(x);
    return (b & 0x80000000u) ? ~b : (b | 0x80000000u);
}
__device__ __forceinline__ float decf(unsigned u) {
    unsigned b = (u & 0x80000000u) ? (u ^ 0x80000000u) : ~u;
    return __uint_as_float(b);
}

// ---------------------------------------------------------------------------
// Pass 1: second moments of feats (32 col sums + 32x32 S2 matrix).
// BN0 stats are linear in these: m = (sum f) @ Wd / N ; E[t^2]_c = w_c^T S2 w_c / N
// ---------------------------------------------------------------------------
__global__ __launch_bounds__(256) void feat_moments_kernel(
    const float* __restrict__ feats, float* __restrict__ red0, int N)
{
    __shared__ float f_lds[64 * 33];  // stride 33 breaks bank aliasing
    int t  = threadIdx.x;
    int i  = t >> 3;        // 0..31
    int j0 = (t & 7) * 4;   // 0,4,...,28
    float a0 = 0.f, a1 = 0.f, a2 = 0.f, a3 = 0.f;
    float s = 0.f;
    int numTiles = (N + 63) >> 6;
    for (int tile = blockIdx.x; tile < numTiles; tile += gridDim.x) {
        int base = tile << 6;
        __syncthreads();
        {
            int jl = t >> 2, sg = (t & 3) * 8;
            int j = base + jl;
            #pragma unroll
            for (int e = 0; e < 8; ++e) {
                float v = 0.f;
                if (j < N) v = feats[(size_t)j * CIN + sg + e];
                f_lds[jl * 33 + sg + e] = v;
            }
        }
        __syncthreads();
        #pragma unroll 4
        for (int r = 0; r < 64; ++r) {
            float fi = f_lds[r * 33 + i];
            a0 += fi * f_lds[r * 33 + j0 + 0];
            a1 += fi * f_lds[r * 33 + j0 + 1];
            a2 += fi * f_lds[r * 33 + j0 + 2];
            a3 += fi * f_lds[r * 33 + j0 + 3];
        }
        if (t < 32) {
            #pragma unroll 4
            for (int r = 0; r < 64; ++r) s += f_lds[r * 33 + t];
        }
    }
    atomicAdd(&red0[32 + i * 32 + j0 + 0], a0);
    atomicAdd(&red0[32 + i * 32 + j0 + 1], a1);
    atomicAdd(&red0[32 + i * 32 + j0 + 2], a2);
    atomicAdd(&red0[32 + i * 32 + j0 + 3], a3);
    if (t < 32) atomicAdd(&red0[t], s);
}

// 1 block x 64 threads: finalize BN0 scale/shift
__global__ void fin0_kernel(const float* __restrict__ red0, const float* __restrict__ Wd,
                            const float* __restrict__ g0, const float* __restrict__ b0,
                            float* __restrict__ scale0, float* __restrict__ shift0, int N)
{
    int c = threadIdx.x;  // 0..63
    float w[CIN];
    #pragma unroll
    for (int i = 0; i < CIN; ++i) w[i] = Wd[i * COUT + c];
    float m = 0.f;
    #pragma unroll
    for (int i = 0; i < CIN; ++i) m += red0[i] * w[i];
    m /= (float)N;
    float q = 0.f;
    for (int i = 0; i < CIN; ++i) {
        const float* row = red0 + 32 + i * 32;
        float p = 0.f;
        #pragma unroll
        for (int j = 0; j < CIN; ++j) p += row[j] * w[j];
        q += w[i] * p;
    }
    float var = q / (float)N - m * m;
    float sc = g0[c] / sqrtf(var + EPSF);
    scale0[c] = sc;
    shift0[c] = b0[c] - m * sc;
}

// ---------------------------------------------------------------------------
// Pass 2: t = feats@Wd (recompute), BN0+ELU, atomicMax scatter into pooled grid
// ---------------------------------------------------------------------------
__global__ __launch_bounds__(256) void gemm_pool_kernel(
    const float* __restrict__ feats, const float* __restrict__ Wd,
    const int* __restrict__ pool_seg,
    const float* __restrict__ scale0, const float* __restrict__ shift0,
    unsigned* __restrict__ down_enc, int N)
{
    __shared__ float f_lds[64 * 33];
    __shared__ float wd_lds[CIN * COUT];
    int t = threadIdx.x;
    int base = blockIdx.x << 6;
    {   // stage Wd (2048 floats)
        const float4* src = (const float4*)Wd;
        float4* dst = (float4*)wd_lds;
        dst[t * 2 + 0] = src[t * 2 + 0];
        dst[t * 2 + 1] = src[t * 2 + 1];
    }
    int jl = t >> 2, sg = t & 3;
    int j = base + jl;
    #pragma unroll
    for (int e = 0; e < 8; ++e) {
        float v = 0.f;
        if (j < N) v = feats[(size_t)j * CIN + sg * 8 + e];
        f_lds[jl * 33 + sg * 8 + e] = v;
    }
    __syncthreads();
    int c0 = sg * 16;
    float acc[16];
    #pragma unroll
    for (int e = 0; e < 16; ++e) acc[e] = 0.f;
    #pragma unroll 4
    for (int i = 0; i < CIN; ++i) {
        float fv = f_lds[jl * 33 + i];
        const float4* wrow = (const float4*)(wd_lds + i * COUT + c0);
        #pragma unroll
        for (int q = 0; q < 4; ++q) {
            float4 w4 = wrow[q];
            acc[q * 4 + 0] += fv * w4.x; acc[q * 4 + 1] += fv * w4.y;
            acc[q * 4 + 2] += fv * w4.z; acc[q * 4 + 3] += fv * w4.w;
        }
    }
    if (j < N) {
        int sgm = pool_seg[j];
        unsigned* dst = down_enc + (size_t)sgm * COUT + c0;
        #pragma unroll
        for (int e = 0; e < 16; ++e) {
            float v = eluf(acc[e] * scale0[c0 + e] + shift0[c0 + e]);
            atomicMax(&dst[e], encf(v));
        }
    }
}

__global__ void decode_kernel(unsigned* __restrict__ d, int n)
{
    int i = blockIdx.x * 256 + threadIdx.x;
    if (i < n) d[i] = __float_as_uint(decf(d[i]));
}

// invert (k, pairlist) maps into nbr[M][27]; missing entries stay -1 (memset 0xFF)
__global__ void nbr_kernel(const int* __restrict__ conv_out, const int* __restrict__ conv_in,
                           int* __restrict__ nbr, int L, int M)
{
    int k = blockIdx.y;
    int idx = blockIdx.x * 256 + threadIdx.x;
    if (idx < L) {
        int e = k * L + idx;
        int j = conv_out[e];
        if (j < M) nbr[(size_t)j * KVOL + k] = conv_in[e];
    }
}

// ---------------------------------------------------------------------------
// Gather-form sparse conv: out[j] = sum_k tf(in[nbr[j][k]]) @ W[k]
// tf = identity (conv1) or ELU(scale*x+shift) (conv2, folds BN1 apply).
// Fused per-channel sum/sumsq stats -> red (for the following BN).
// ---------------------------------------------------------------------------
__global__ __launch_bounds__(256) void conv_kernel(
    const float* __restrict__ in, const float* __restrict__ W,
    const int* __restrict__ nbr, int M,
    const float* __restrict__ in_scale, const float* __restrict__ in_shift, int apply_tf,
    float* __restrict__ out, float* __restrict__ red)
{
    __shared__ float w_lds[COUT * COUT];   // 16 KB
    __shared__ float h_lds[64 * 72];       // stride 72: bank-spread + 16B aligned
    int t = threadIdx.x;
    int jl = t >> 2, sg = t & 3, c0 = sg * 16;
    int base = blockIdx.x << 6;
    int j = base + jl;

    float sc[16], sh[16];
    if (apply_tf) {
        #pragma unroll
        for (int e = 0; e < 16; ++e) { sc[e] = in_scale[c0 + e]; sh[e] = in_shift[c0 + e]; }
    }
    float acc[16];
    #pragma unroll
    for (int e = 0; e < 16; ++e) acc[e] = 0.f;

    for (int k = 0; k < KVOL; ++k) {
        __syncthreads();
        {   // stage W[k] (4096 floats)
            const float4* src = (const float4*)(W + (size_t)k * COUT * COUT);
            float4* dst = (float4*)w_lds;
            #pragma unroll
            for (int q = 0; q < 4; ++q) dst[t * 4 + q] = src[t * 4 + q];
        }
        {   // stage gathered h rows
            int idx = -1;
            if (j < M) idx = nbr[(size_t)j * KVOL + k];
            float4 hv[4];
            if (idx >= 0) {
                const float4* src = (const float4*)(in + (size_t)idx * COUT + c0);
                #pragma unroll
                for (int q = 0; q < 4; ++q) hv[q] = src[q];
                if (apply_tf) {
                    #pragma unroll
                    for (int q = 0; q < 4; ++q) {
                        hv[q].x = eluf(hv[q].x * sc[q*4+0] + sh[q*4+0]);
                        hv[q].y = eluf(hv[q].y * sc[q*4+1] + sh[q*4+1]);
                        hv[q].z = eluf(hv[q].z * sc[q*4+2] + sh[q*4+2]);
                        hv[q].w = eluf(hv[q].w * sc[q*4+3] + sh[q*4+3]);
                    }
                }
            } else {
                #pragma unroll
                for (int q = 0; q < 4; ++q) hv[q] = make_float4(0.f, 0.f, 0.f, 0.f);
            }
            float4* hd = (float4*)(h_lds + jl * 72 + c0);
            #pragma unroll
            for (int q = 0; q < 4; ++q) hd[q] = hv[q];
        }
        __syncthreads();
        #pragma unroll 4
        for (int i = 0; i < COUT; i += 4) {
            float4 h4 = *(const float4*)(h_lds + jl * 72 + i);
            #pragma unroll
            for (int u = 0; u < 4; ++u) {
                float hv = (u == 0) ? h4.x : (u == 1) ? h4.y : (u == 2) ? h4.z : h4.w;
                const float4* wrow = (const float4*)(w_lds + (i + u) * COUT + c0);
                #pragma unroll
                for (int q = 0; q < 4; ++q) {
                    float4 w4 = wrow[q];
                    acc[q*4+0] += hv * w4.x; acc[q*4+1] += hv * w4.y;
                    acc[q*4+2] += hv * w4.z; acc[q*4+3] += hv * w4.w;
                }
            }
        }
    }
    if (j < M) {
        float4* dst = (float4*)(out + (size_t)j * COUT + c0);
        #pragma unroll
        for (int q = 0; q < 4; ++q)
            dst[q] = make_float4(acc[q*4+0], acc[q*4+1], acc[q*4+2], acc[q*4+3]);
    }
    // fused BN stats: rows beyond M contribute exact zeros
    float s1[16], sq[16];
    #pragma unroll
    for (int e = 0; e < 16; ++e) { s1[e] = acc[e]; sq[e] = acc[e] * acc[e]; }
    #pragma unroll
    for (int mask = 4; mask <= 32; mask <<= 1) {
        #pragma unroll
        for (int e = 0; e < 16; ++e) {
            s1[e] += __shfl_xor(s1[e], mask, 64);
            sq[e] += __shfl_xor(sq[e], mask, 64);
        }
    }
    __syncthreads();  // safe to reuse h_lds
    int lane = t & 63, wv = t >> 6;
    if (lane < 4) {
        float* p = h_lds + wv * 128 + lane * 32;
        #pragma unroll
        for (int e = 0; e < 16; ++e) { p[e] = s1[e]; p[16 + e] = sq[e]; }
    }
    __syncthreads();
    if (t < 128) {
        int c = t & 63, st = t >> 6;
        int g = c >> 4, cc = c & 15;
        float v = 0.f;
        #pragma unroll
        for (int w = 0; w < 4; ++w) v += h_lds[w * 128 + g * 32 + st * 16 + cc];
        atomicAdd(&red[st * 64 + c], v);
    }
}

__global__ void finC_kernel(const float* __restrict__ red, const float* __restrict__ g,
                            const float* __restrict__ b, float* __restrict__ scale,
                            float* __restrict__ shift, int M)
{
    int c = threadIdx.x;  // 64
    float m = red[c] / (float)M;
    float var = red[64 + c] / (float)M - m * m;
    float sc = g[c] / sqrtf(var + EPSF);
    scale[c] = sc;
    shift[c] = b[c] - m * sc;
}

// out = elu( elu(scale2*raw + shift2) + down )
__global__ void final_kernel(float* __restrict__ out, const float* __restrict__ down,
                             const float* __restrict__ scale2, const float* __restrict__ shift2,
                             int n)
{
    int i = blockIdx.x * 256 + threadIdx.x;
    if (i < n) {
        int c = i & 63;
        float y = eluf(out[i] * scale2[c] + shift2[c]);
        out[i] = eluf(y + down[i]);
    }
}

extern "C" void kernel_launch(void* const* d_in, const int* in_sizes, int n_in,
                              void* d_out, int out_size, void* d_ws, size_t ws_size,
                              hipStream_t stream)
{
    (void)n_in; (void)ws_size;
    const float* feats    = (const float*)d_in[0];
    const float* Wd       = (const float*)d_in[1];
    const float* g0       = (const float*)d_in[2];
    const float* b0       = (const float*)d_in[3];
    const float* W1       = (const float*)d_in[4];
    const float* g1       = (const float*)d_in[5];
    const float* b1       = (const float*)d_in[6];
    const float* W2       = (const float*)d_in[7];
    const float* g2       = (const float*)d_in[8];
    const float* b2       = (const float*)d_in[9];
    const int*   pool_seg = (const int*)d_in[10];
    const int*   conv_in  = (const int*)d_in[11];
    const int*   conv_out = (const int*)d_in[12];
    // d_in[13] = num_pooled (device scalar); M recovered from out_size instead

    int N = in_sizes[0] / CIN;
    int M = out_size / COUT;
    int L = in_sizes[11] / KVOL;

    char* ws = (char*)d_ws;
    size_t off = 0;
    auto alloc = [&](size_t bytes) -> void* {
        void* p = ws + off;
        off = (off + bytes + 255) & ~(size_t)255;
        return p;
    };
    float* down = (float*)alloc((size_t)M * COUT * 4);
    float* o1   = (float*)alloc((size_t)M * COUT * 4);
    int*   nbr  = (int*)alloc((size_t)M * KVOL * 4);
    float* red  = (float*)alloc((size_t)(1056 + 128 + 128) * 4);
    float* red0 = red, *red1 = red + 1056, *red2 = red + 1056 + 128;
    float* sreg = (float*)alloc((size_t)6 * 64 * 4);
    float* scale0 = sreg, *shift0 = sreg + 64;
    float* scale1 = sreg + 128, *shift1 = sreg + 192;
    float* scale2 = sreg + 256, *shift2 = sreg + 320;

    hipMemsetAsync(down, 0, (size_t)M * COUT * 4, stream);          // enc(-inf) sentinel base
    hipMemsetAsync(nbr, 0xFF, (size_t)M * KVOL * 4, stream);        // -1 = missing neighbor
    hipMemsetAsync(red, 0, (size_t)(1056 + 128 + 128) * 4, stream); // stat accumulators

    feat_moments_kernel<<<1024, 256, 0, stream>>>(feats, red0, N);
    fin0_kernel<<<1, 64, 0, stream>>>(red0, Wd, g0, b0, scale0, shift0, N);
    gemm_pool_kernel<<<(N + 63) / 64, 256, 0, stream>>>(
        feats, Wd, pool_seg, scale0, shift0, (unsigned*)down, N);
    decode_kernel<<<(M * COUT + 255) / 256, 256, 0, stream>>>((unsigned*)down, M * COUT);
    dim3 gn((L + 255) / 256, KVOL);
    nbr_kernel<<<gn, 256, 0, stream>>>(conv_out, conv_in, nbr, L, M);

    int cblocks = (M + 63) / 64;
    conv_kernel<<<cblocks, 256, 0, stream>>>(down, W1, nbr, M, nullptr, nullptr, 0, o1, red1);
    finC_kernel<<<1, 64, 0, stream>>>(red1, g1, b1, scale1, shift1, M);
    conv_kernel<<<cblocks, 256, 0, stream>>>(o1, W2, nbr, M, scale1, shift1, 1, (float*)d_out, red2);
    finC_kernel<<<1, 64, 0, stream>>>(red2, g2, b2, scale2, shift2, M);
    final_kernel<<<(M * COUT + 255) / 256, 256, 0, stream>>>(
        (float*)d_out, down, scale2, shift2, M * COUT);
}

// Round 2
// 2483.541 us; speedup vs baseline: 1.5455x; 1.5455x over previous
//
#include <hip/hip_runtime.h>
#include <math.h>

#define CIN  32
#define COUT 64
#define KVOL 27
#define EPSF 1e-5f

__device__ __forceinline__ float eluf(float x) { return x > 0.f ? x : expm1f(x); }

// ---------------------------------------------------------------------------
// Pass 1: second moments of feats (32 col sums + 32x32 S2 matrix).
// BN0 stats are linear in these: m = (sum f) @ Wd / N ; E[t^2]_c = w_c^T S2 w_c / N
// ---------------------------------------------------------------------------
__global__ __launch_bounds__(256) void feat_moments_kernel(
    const float* __restrict__ feats, float* __restrict__ red0, int N)
{
    __shared__ float f_lds[64 * 33];  // stride 33 breaks bank aliasing
    int t  = threadIdx.x;
    int i  = t >> 3;        // 0..31
    int j0 = (t & 7) * 4;   // 0,4,...,28
    float a0 = 0.f, a1 = 0.f, a2 = 0.f, a3 = 0.f;
    float s = 0.f;
    int numTiles = (N + 63) >> 6;
    for (int tile = blockIdx.x; tile < numTiles; tile += gridDim.x) {
        int base = tile << 6;
        __syncthreads();
        {
            int jl = t >> 2, sg = (t & 3) * 8;
            int j = base + jl;
            #pragma unroll
            for (int e = 0; e < 8; ++e) {
                float v = 0.f;
                if (j < N) v = feats[(size_t)j * CIN + sg + e];
                f_lds[jl * 33 + sg + e] = v;
            }
        }
        __syncthreads();
        #pragma unroll 4
        for (int r = 0; r < 64; ++r) {
            float fi = f_lds[r * 33 + i];
            a0 += fi * f_lds[r * 33 + j0 + 0];
            a1 += fi * f_lds[r * 33 + j0 + 1];
            a2 += fi * f_lds[r * 33 + j0 + 2];
            a3 += fi * f_lds[r * 33 + j0 + 3];
        }
        if (t < 32) {
            #pragma unroll 4
            for (int r = 0; r < 64; ++r) s += f_lds[r * 33 + t];
        }
    }
    atomicAdd(&red0[32 + i * 32 + j0 + 0], a0);
    atomicAdd(&red0[32 + i * 32 + j0 + 1], a1);
    atomicAdd(&red0[32 + i * 32 + j0 + 2], a2);
    atomicAdd(&red0[32 + i * 32 + j0 + 3], a3);
    if (t < 32) atomicAdd(&red0[t], s);
}

// 1 block x 64 threads: finalize BN0 scale/shift
__global__ void fin0_kernel(const float* __restrict__ red0, const float* __restrict__ Wd,
                            const float* __restrict__ g0, const float* __restrict__ b0,
                            float* __restrict__ scale0, float* __restrict__ shift0, int N)
{
    int c = threadIdx.x;  // 0..63
    float w[CIN];
    #pragma unroll
    for (int i = 0; i < CIN; ++i) w[i] = Wd[i * COUT + c];
    float m = 0.f;
    #pragma unroll
    for (int i = 0; i < CIN; ++i) m += red0[i] * w[i];
    m /= (float)N;
    float q = 0.f;
    for (int i = 0; i < CIN; ++i) {
        const float* row = red0 + 32 + i * 32;
        float p = 0.f;
        #pragma unroll
        for (int j = 0; j < CIN; ++j) p += row[j] * w[j];
        q += w[i] * p;
    }
    float var = q / (float)N - m * m;
    float sc = g0[c] / sqrtf(var + EPSF);
    scale0[c] = sc;
    shift0[c] = b0[c] - m * sc;
}

// ---------------------------------------------------------------------------
// Bucket build: pooling cell = 2x2x4 = 16 voxels max -> fixed capacity 16,
// no prefix scan needed. 600k int atomics (contention <= 16).
// ---------------------------------------------------------------------------
__global__ void bucket_kernel(const int* __restrict__ pool_seg,
                              int* __restrict__ cnt, int* __restrict__ bucket, int N)
{
    int j = blockIdx.x * 256 + threadIdx.x;
    if (j < N) {
        int s = pool_seg[j];
        int pos = atomicAdd(&cnt[s], 1);
        bucket[(size_t)s * 16 + pos] = j;
    }
}

// ---------------------------------------------------------------------------
// Gather-form pool: one wave per segment, lane = out channel.
// For each member point, recompute its down-conv row (feats@Wd), BN0+ELU,
// running max. No atomics, no N x COUT intermediate.
// ---------------------------------------------------------------------------
__global__ __launch_bounds__(256) void pool_kernel(
    const float* __restrict__ feats, const float* __restrict__ Wd,
    const int* __restrict__ cnt, const int* __restrict__ bucket,
    const float* __restrict__ scale0, const float* __restrict__ shift0,
    float* __restrict__ down, int M)
{
    __shared__ float wd_lds[CIN * COUT];  // 8 KB
    int t = threadIdx.x;
    {   // stage Wd (2048 floats) cooperatively
        const float4* src = (const float4*)Wd;
        float4* dst = (float4*)wd_lds;
        dst[t * 2 + 0] = src[t * 2 + 0];
        dst[t * 2 + 1] = src[t * 2 + 1];
    }
    __syncthreads();
    int s = blockIdx.x * 4 + (t >> 6);
    int c = t & 63;
    if (s >= M) return;
    float sc = scale0[c], sh = shift0[c];
    int n = cnt[s];
    const int* bk = bucket + (size_t)s * 16;
    float m = -INFINITY;
    for (int p = 0; p < n; ++p) {
        int idx = bk[p];
        const float4* fr = (const float4*)(feats + (size_t)idx * CIN);
        float acc = 0.f;
        #pragma unroll
        for (int q = 0; q < 8; ++q) {
            float4 f4 = fr[q];
            acc += f4.x * wd_lds[(q * 4 + 0) * COUT + c];
            acc += f4.y * wd_lds[(q * 4 + 1) * COUT + c];
            acc += f4.z * wd_lds[(q * 4 + 2) * COUT + c];
            acc += f4.w * wd_lds[(q * 4 + 3) * COUT + c];
        }
        float y = eluf(acc * sc + sh);
        m = fmaxf(m, y);
    }
    down[(size_t)s * COUT + c] = m;
}

// invert (k, pairlist) maps into nbr[M][27]; missing entries stay -1 (memset 0xFF)
__global__ void nbr_kernel(const int* __restrict__ conv_out, const int* __restrict__ conv_in,
                           int* __restrict__ nbr, int L, int M)
{
    int k = blockIdx.y;
    int idx = blockIdx.x * 256 + threadIdx.x;
    if (idx < L) {
        int e = k * L + idx;
        int j = conv_out[e];
        if (j < M) nbr[(size_t)j * KVOL + k] = conv_in[e];
    }
}

// ---------------------------------------------------------------------------
// Gather-form sparse conv: out[j] = sum_k tf(in[nbr[j][k]]) @ W[k]
// tf = identity (conv1) or ELU(scale*x+shift) (conv2, folds BN1 apply).
// Fused per-channel sum/sumsq stats -> red (for the following BN).
// ---------------------------------------------------------------------------
__global__ __launch_bounds__(256) void conv_kernel(
    const float* __restrict__ in, const float* __restrict__ W,
    const int* __restrict__ nbr, int M,
    const float* __restrict__ in_scale, const float* __restrict__ in_shift, int apply_tf,
    float* __restrict__ out, float* __restrict__ red)
{
    __shared__ float w_lds[COUT * COUT];   // 16 KB
    __shared__ float h_lds[64 * 72];       // stride 72: bank-spread + 16B aligned
    int t = threadIdx.x;
    int jl = t >> 2, sg = t & 3, c0 = sg * 16;
    int base = blockIdx.x << 6;
    int j = base + jl;

    float sc[16], sh[16];
    if (apply_tf) {
        #pragma unroll
        for (int e = 0; e < 16; ++e) { sc[e] = in_scale[c0 + e]; sh[e] = in_shift[c0 + e]; }
    }
    float acc[16];
    #pragma unroll
    for (int e = 0; e < 16; ++e) acc[e] = 0.f;

    for (int k = 0; k < KVOL; ++k) {
        __syncthreads();
        {   // stage W[k] (4096 floats)
            const float4* src = (const float4*)(W + (size_t)k * COUT * COUT);
            float4* dst = (float4*)w_lds;
            #pragma unroll
            for (int q = 0; q < 4; ++q) dst[t * 4 + q] = src[t * 4 + q];
        }
        {   // stage gathered h rows
            int idx = -1;
            if (j < M) idx = nbr[(size_t)j * KVOL + k];
            float4 hv[4];
            if (idx >= 0) {
                const float4* src = (const float4*)(in + (size_t)idx * COUT + c0);
                #pragma unroll
                for (int q = 0; q < 4; ++q) hv[q] = src[q];
                if (apply_tf) {
                    #pragma unroll
                    for (int q = 0; q < 4; ++q) {
                        hv[q].x = eluf(hv[q].x * sc[q*4+0] + sh[q*4+0]);
                        hv[q].y = eluf(hv[q].y * sc[q*4+1] + sh[q*4+1]);
                        hv[q].z = eluf(hv[q].z * sc[q*4+2] + sh[q*4+2]);
                        hv[q].w = eluf(hv[q].w * sc[q*4+3] + sh[q*4+3]);
                    }
                }
            } else {
                #pragma unroll
                for (int q = 0; q < 4; ++q) hv[q] = make_float4(0.f, 0.f, 0.f, 0.f);
            }
            float4* hd = (float4*)(h_lds + jl * 72 + c0);
            #pragma unroll
            for (int q = 0; q < 4; ++q) hd[q] = hv[q];
        }
        __syncthreads();
        #pragma unroll 4
        for (int i = 0; i < COUT; i += 4) {
            float4 h4 = *(const float4*)(h_lds + jl * 72 + i);
            #pragma unroll
            for (int u = 0; u < 4; ++u) {
                float hv = (u == 0) ? h4.x : (u == 1) ? h4.y : (u == 2) ? h4.z : h4.w;
                const float4* wrow = (const float4*)(w_lds + (i + u) * COUT + c0);
                #pragma unroll
                for (int q = 0; q < 4; ++q) {
                    float4 w4 = wrow[q];
                    acc[q*4+0] += hv * w4.x; acc[q*4+1] += hv * w4.y;
                    acc[q*4+2] += hv * w4.z; acc[q*4+3] += hv * w4.w;
                }
            }
        }
    }
    if (j < M) {
        float4* dst = (float4*)(out + (size_t)j * COUT + c0);
        #pragma unroll
        for (int q = 0; q < 4; ++q)
            dst[q] = make_float4(acc[q*4+0], acc[q*4+1], acc[q*4+2], acc[q*4+3]);
    }
    // fused BN stats: rows beyond M contribute exact zeros
    float s1[16], sq[16];
    #pragma unroll
    for (int e = 0; e < 16; ++e) { s1[e] = acc[e]; sq[e] = acc[e] * acc[e]; }
    #pragma unroll
    for (int mask = 4; mask <= 32; mask <<= 1) {
        #pragma unroll
        for (int e = 0; e < 16; ++e) {
            s1[e] += __shfl_xor(s1[e], mask, 64);
            sq[e] += __shfl_xor(sq[e], mask, 64);
        }
    }
    __syncthreads();  // safe to reuse h_lds
    int lane = t & 63, wv = t >> 6;
    if (lane < 4) {
        float* p = h_lds + wv * 128 + lane * 32;
        #pragma unroll
        for (int e = 0; e < 16; ++e) { p[e] = s1[e]; p[16 + e] = sq[e]; }
    }
    __syncthreads();
    if (t < 128) {
        int c = t & 63, st = t >> 6;
        int g = c >> 4, cc = c & 15;
        float v = 0.f;
        #pragma unroll
        for (int w = 0; w < 4; ++w) v += h_lds[w * 128 + g * 32 + st * 16 + cc];
        atomicAdd(&red[st * 64 + c], v);
    }
}

__global__ void finC_kernel(const float* __restrict__ red, const float* __restrict__ g,
                            const float* __restrict__ b, float* __restrict__ scale,
                            float* __restrict__ shift, int M)
{
    int c = threadIdx.x;  // 64
    float m = red[c] / (float)M;
    float var = red[64 + c] / (float)M - m * m;
    float sc = g[c] / sqrtf(var + EPSF);
    scale[c] = sc;
    shift[c] = b[c] - m * sc;
}

// out = elu( elu(scale2*raw + shift2) + down )
__global__ void final_kernel(float* __restrict__ out, const float* __restrict__ down,
                             const float* __restrict__ scale2, const float* __restrict__ shift2,
                             int n)
{
    int i = blockIdx.x * 256 + threadIdx.x;
    if (i < n) {
        int c = i & 63;
        float y = eluf(out[i] * scale2[c] + shift2[c]);
        out[i] = eluf(y + down[i]);
    }
}

extern "C" void kernel_launch(void* const* d_in, const int* in_sizes, int n_in,
                              void* d_out, int out_size, void* d_ws, size_t ws_size,
                              hipStream_t stream)
{
    (void)n_in; (void)ws_size;
    const float* feats    = (const float*)d_in[0];
    const float* Wd       = (const float*)d_in[1];
    const float* g0       = (const float*)d_in[2];
    const float* b0       = (const float*)d_in[3];
    const float* W1       = (const float*)d_in[4];
    const float* g1       = (const float*)d_in[5];
    const float* b1       = (const float*)d_in[6];
    const float* W2       = (const float*)d_in[7];
    const float* g2       = (const float*)d_in[8];
    const float* b2       = (const float*)d_in[9];
    const int*   pool_seg = (const int*)d_in[10];
    const int*   conv_in  = (const int*)d_in[11];
    const int*   conv_out = (const int*)d_in[12];

    int N = in_sizes[0] / CIN;
    int M = out_size / COUT;
    int L = in_sizes[11] / KVOL;

    char* ws = (char*)d_ws;
    size_t off = 0;
    auto alloc = [&](size_t bytes) -> void* {
        void* p = ws + off;
        off = (off + bytes + 255) & ~(size_t)255;
        return p;
    };
    float* down   = (float*)alloc((size_t)M * COUT * 4);
    float* o1     = (float*)alloc((size_t)M * COUT * 4);
    int*   nbr    = (int*)alloc((size_t)M * KVOL * 4);
    int*   cnt    = (int*)alloc((size_t)M * 4);
    int*   bucket = (int*)alloc((size_t)M * 16 * 4);
    float* red  = (float*)alloc((size_t)(1056 + 128 + 128) * 4);
    float* red0 = red, *red1 = red + 1056, *red2 = red + 1056 + 128;
    float* sreg = (float*)alloc((size_t)6 * 64 * 4);
    float* scale0 = sreg, *shift0 = sreg + 64;
    float* scale1 = sreg + 128, *shift1 = sreg + 192;
    float* scale2 = sreg + 256, *shift2 = sreg + 320;

    hipMemsetAsync(nbr, 0xFF, (size_t)M * KVOL * 4, stream);        // -1 = missing neighbor
    hipMemsetAsync(cnt, 0, (size_t)M * 4, stream);                  // bucket counters
    hipMemsetAsync(red, 0, (size_t)(1056 + 128 + 128) * 4, stream); // stat accumulators

    feat_moments_kernel<<<1024, 256, 0, stream>>>(feats, red0, N);
    fin0_kernel<<<1, 64, 0, stream>>>(red0, Wd, g0, b0, scale0, shift0, N);
    bucket_kernel<<<(N + 255) / 256, 256, 0, stream>>>(pool_seg, cnt, bucket, N);
    pool_kernel<<<(M + 3) / 4, 256, 0, stream>>>(
        feats, Wd, cnt, bucket, scale0, shift0, down, M);
    dim3 gn((L + 255) / 256, KVOL);
    nbr_kernel<<<gn, 256, 0, stream>>>(conv_out, conv_in, nbr, L, M);

    int cblocks = (M + 63) / 64;
    conv_kernel<<<cblocks, 256, 0, stream>>>(down, W1, nbr, M, nullptr, nullptr, 0, o1, red1);
    finC_kernel<<<1, 64, 0, stream>>>(red1, g1, b1, scale1, shift1, M);
    conv_kernel<<<cblocks, 256, 0, stream>>>(o1, W2, nbr, M, scale1, shift1, 1, (float*)d_out, red2);
    finC_kernel<<<1, 64, 0, stream>>>(red2, g2, b2, scale2, shift2, M);
    final_kernel<<<(M * COUT + 255) / 256, 256, 0, stream>>>(
        (float*)d_out, down, scale2, shift2, M * COUT);
}

// Round 3
// 908.538 us; speedup vs baseline: 4.2247x; 2.7336x over previous
//
#include <hip/hip_runtime.h>
#include <math.h>

#define CIN  32
#define COUT 64
#define KVOL 27
#define EPSF 1e-5f

typedef __attribute__((ext_vector_type(8))) short          short8;
typedef __attribute__((ext_vector_type(8))) unsigned short u16x8;
typedef __attribute__((ext_vector_type(4))) float          float4v;

__device__ __forceinline__ float eluf(float x) { return x > 0.f ? x : expm1f(x); }

// f32 -> bf16 round-to-nearest-even
__device__ __forceinline__ unsigned short f2bf(float x) {
    unsigned u = __float_as_uint(x);
    unsigned r = (u + 0x7FFFu + ((u >> 16) & 1u)) >> 16;
    return (unsigned short)r;
}

// ---------------------------------------------------------------------------
// Pass 1: second moments of feats (32 col sums + 32x32 S2 matrix).
// BN0 stats are linear in these: m = (sum f) @ Wd / N ; E[t^2]_c = w_c^T S2 w_c / N
// ---------------------------------------------------------------------------
__global__ __launch_bounds__(256) void feat_moments_kernel(
    const float* __restrict__ feats, float* __restrict__ red0, int N)
{
    __shared__ float f_lds[64 * 33];  // stride 33 breaks bank aliasing
    int t  = threadIdx.x;
    int i  = t >> 3;        // 0..31
    int j0 = (t & 7) * 4;   // 0,4,...,28
    float a0 = 0.f, a1 = 0.f, a2 = 0.f, a3 = 0.f;
    float s = 0.f;
    int numTiles = (N + 63) >> 6;
    for (int tile = blockIdx.x; tile < numTiles; tile += gridDim.x) {
        int base = tile << 6;
        __syncthreads();
        {
            int jl = t >> 2, sg = (t & 3) * 8;
            int j = base + jl;
            #pragma unroll
            for (int e = 0; e < 8; ++e) {
                float v = 0.f;
                if (j < N) v = feats[(size_t)j * CIN + sg + e];
                f_lds[jl * 33 + sg + e] = v;
            }
        }
        __syncthreads();
        #pragma unroll 4
        for (int r = 0; r < 64; ++r) {
            float fi = f_lds[r * 33 + i];
            a0 += fi * f_lds[r * 33 + j0 + 0];
            a1 += fi * f_lds[r * 33 + j0 + 1];
            a2 += fi * f_lds[r * 33 + j0 + 2];
            a3 += fi * f_lds[r * 33 + j0 + 3];
        }
        if (t < 32) {
            #pragma unroll 4
            for (int r = 0; r < 64; ++r) s += f_lds[r * 33 + t];
        }
    }
    atomicAdd(&red0[32 + i * 32 + j0 + 0], a0);
    atomicAdd(&red0[32 + i * 32 + j0 + 1], a1);
    atomicAdd(&red0[32 + i * 32 + j0 + 2], a2);
    atomicAdd(&red0[32 + i * 32 + j0 + 3], a3);
    if (t < 32) atomicAdd(&red0[t], s);
}

// 1 block x 64 threads: finalize BN0 scale/shift
__global__ void fin0_kernel(const float* __restrict__ red0, const float* __restrict__ Wd,
                            const float* __restrict__ g0, const float* __restrict__ b0,
                            float* __restrict__ scale0, float* __restrict__ shift0, int N)
{
    int c = threadIdx.x;  // 0..63
    float w[CIN];
    #pragma unroll
    for (int i = 0; i < CIN; ++i) w[i] = Wd[i * COUT + c];
    float m = 0.f;
    #pragma unroll
    for (int i = 0; i < CIN; ++i) m += red0[i] * w[i];
    m /= (float)N;
    float q = 0.f;
    for (int i = 0; i < CIN; ++i) {
        const float* row = red0 + 32 + i * 32;
        float p = 0.f;
        #pragma unroll
        for (int j = 0; j < CIN; ++j) p += row[j] * w[j];
        q += w[i] * p;
    }
    float var = q / (float)N - m * m;
    float sc = g0[c] / sqrtf(var + EPSF);
    scale0[c] = sc;
    shift0[c] = b0[c] - m * sc;
}

// ---------------------------------------------------------------------------
// Bucket build: pooling cell = 2x2x4 = 16 voxels max -> fixed capacity 16.
// ---------------------------------------------------------------------------
__global__ void bucket_kernel(const int* __restrict__ pool_seg,
                              int* __restrict__ cnt, int* __restrict__ bucket, int N)
{
    int j = blockIdx.x * 256 + threadIdx.x;
    if (j < N) {
        int s = pool_seg[j];
        int pos = atomicAdd(&cnt[s], 1);
        bucket[(size_t)s * 16 + pos] = j;
    }
}

// ---------------------------------------------------------------------------
// Gather-form pool: one wave per segment, lane = out channel. Writes f32
// (residual path) + bf16 (conv1 A-matrix).
// ---------------------------------------------------------------------------
__global__ __launch_bounds__(256) void pool_kernel(
    const float* __restrict__ feats, const float* __restrict__ Wd,
    const int* __restrict__ cnt, const int* __restrict__ bucket,
    const float* __restrict__ scale0, const float* __restrict__ shift0,
    float* __restrict__ down, unsigned short* __restrict__ down_bf, int M)
{
    __shared__ float wd_lds[CIN * COUT];  // 8 KB
    int t = threadIdx.x;
    {   // stage Wd (2048 floats) cooperatively
        const float4* src = (const float4*)Wd;
        float4* dst = (float4*)wd_lds;
        dst[t * 2 + 0] = src[t * 2 + 0];
        dst[t * 2 + 1] = src[t * 2 + 1];
    }
    __syncthreads();
    int s = blockIdx.x * 4 + (t >> 6);
    int c = t & 63;
    if (s >= M) return;
    float sc = scale0[c], sh = shift0[c];
    int n = cnt[s];
    const int* bk = bucket + (size_t)s * 16;
    float m = -INFINITY;
    for (int p = 0; p < n; ++p) {
        int idx = bk[p];
        const float4* fr = (const float4*)(feats + (size_t)idx * CIN);
        float acc = 0.f;
        #pragma unroll
        for (int q = 0; q < 8; ++q) {
            float4 f4 = fr[q];
            acc += f4.x * wd_lds[(q * 4 + 0) * COUT + c];
            acc += f4.y * wd_lds[(q * 4 + 1) * COUT + c];
            acc += f4.z * wd_lds[(q * 4 + 2) * COUT + c];
            acc += f4.w * wd_lds[(q * 4 + 3) * COUT + c];
        }
        float y = eluf(acc * sc + sh);
        m = fmaxf(m, y);
    }
    down[(size_t)s * COUT + c] = m;
    down_bf[(size_t)s * COUT + c] = f2bf(m);
}

// invert (k, pairlist) maps into nbrT[k][M] (transposed for coalesced conv reads)
__global__ void nbr_kernel(const int* __restrict__ conv_out, const int* __restrict__ conv_in,
                           int* __restrict__ nbrT, int L, int M)
{
    int k = blockIdx.y;
    int idx = blockIdx.x * 256 + threadIdx.x;
    if (idx < L) {
        int e = k * L + idx;
        int j = conv_out[e];
        if (j < M) nbrT[(size_t)k * M + j] = conv_in[e];
    }
}

// W[k][i][c] (f32) -> Wt[k][c][i] (bf16): B-operand frags become contiguous
__global__ void cvt_w_kernel(const float* __restrict__ W1, const float* __restrict__ W2,
                             unsigned short* __restrict__ Wt1, unsigned short* __restrict__ Wt2)
{
    int b = blockIdx.x;  // 0..53
    const float* W = (b < 27) ? W1 : W2;
    unsigned short* Wt = (b < 27) ? Wt1 : Wt2;
    int k = (b < 27) ? b : b - 27;
    int t = threadIdx.x;
    const float* src = W + (size_t)k * (COUT * COUT);
    unsigned short* dst = Wt + (size_t)k * (COUT * COUT);
    for (int e = t; e < COUT * COUT; e += 256) {
        int i = e >> 6, c = e & 63;
        dst[c * COUT + i] = f2bf(src[e]);
    }
}

// o1t = bf16( ELU(scale1*o1 + shift1) )  -- conv2's A-matrix
__global__ void bn_elu_cvt_kernel(const float* __restrict__ o1,
                                  const float* __restrict__ scale,
                                  const float* __restrict__ shift,
                                  unsigned short* __restrict__ o1t, int n)
{
    int i = blockIdx.x * 256 + threadIdx.x;
    if (i < n) {
        int c = i & 63;
        o1t[i] = f2bf(eluf(o1[i] * scale[c] + shift[c]));
    }
}

// ---------------------------------------------------------------------------
// MFMA implicit-GEMM sparse conv. Block = 128 rows x 64 cols, 4 waves.
// K-loop: 27 offsets x K=64 (2x mfma_f32_16x16x32_bf16 per col tile).
// A staged via gather (zero row if neighbor missing); W^T staged per offset.
// LDS rows stride-72 bf16 (144 B): 16B-aligned, frag reads 2-way = free.
// Fused BN stats epilogue -> red[0..63]=sum, red[64..127]=sumsq.
// ---------------------------------------------------------------------------
__global__ __launch_bounds__(256) void conv_mfma_kernel(
    const unsigned short* __restrict__ in, const unsigned short* __restrict__ Wt,
    const int* __restrict__ nbrT, int M,
    float* __restrict__ out, float* __restrict__ red)
{
    __shared__ __align__(16) unsigned short A_lds[128 * 72];  // 18.4 KB
    __shared__ __align__(16) unsigned short W_lds[64 * 72];   //  9.2 KB
    __shared__ float red_s[64];
    __shared__ float red_q[64];
    int t = threadIdx.x;
    int base = blockIdx.x * 128;
    int w = t >> 6, lane = t & 63, l15 = lane & 15, quad = lane >> 4;

    if (t < 64) { red_s[t] = 0.f; red_q[t] = 0.f; }

    float4v acc[2][4];
    #pragma unroll
    for (int s = 0; s < 2; ++s)
        #pragma unroll
        for (int n = 0; n < 4; ++n)
            acc[s][n] = (float4v){0.f, 0.f, 0.f, 0.f};

    int ar = t >> 1, ah = t & 1;   // A staging: row, 64B-half
    int gj = base + ar;
    int wc = t >> 2, wq = t & 3;   // W staging: row, 32B-chunk

    for (int k = 0; k < KVOL; ++k) {
        __syncthreads();
        {   // stage A: gathered rows (2 threads/row, 64 B each)
            int idx = (gj < M) ? nbrT[(size_t)k * M + gj] : -1;
            u16x8 c0 = {0,0,0,0,0,0,0,0}, c1 = c0, c2 = c0, c3 = c0;
            if (idx >= 0) {
                const u16x8* src = (const u16x8*)(in + (size_t)idx * COUT + 32 * ah);
                c0 = src[0]; c1 = src[1]; c2 = src[2]; c3 = src[3];
            }
            u16x8* dst = (u16x8*)(A_lds + ar * 72 + 32 * ah);
            dst[0] = c0; dst[1] = c1; dst[2] = c2; dst[3] = c3;
        }
        {   // stage Wt[k] (8 KB)
            const u16x8* src = (const u16x8*)(Wt + (size_t)k * (COUT * COUT) + wc * COUT + 16 * wq);
            u16x8* dst = (u16x8*)(W_lds + wc * 72 + 16 * wq);
            dst[0] = src[0]; dst[1] = src[1];
        }
        __syncthreads();
        #pragma unroll
        for (int kk = 0; kk < 64; kk += 32) {
            short8 a0 = *(const short8*)(A_lds + (32 * w + l15) * 72 + kk + quad * 8);
            short8 a1 = *(const short8*)(A_lds + (32 * w + 16 + l15) * 72 + kk + quad * 8);
            #pragma unroll
            for (int n = 0; n < 4; ++n) {
                short8 b = *(const short8*)(W_lds + (16 * n + l15) * 72 + kk + quad * 8);
                acc[0][n] = __builtin_amdgcn_mfma_f32_16x16x32_bf16(a0, b, acc[0][n], 0, 0, 0);
                acc[1][n] = __builtin_amdgcn_mfma_f32_16x16x32_bf16(a1, b, acc[1][n], 0, 0, 0);
            }
        }
    }

    // stores (C/D layout: col=lane&15, row=quad*4+reg)
    #pragma unroll
    for (int s = 0; s < 2; ++s) {
        int row = base + 32 * w + 16 * s + quad * 4;
        #pragma unroll
        for (int n = 0; n < 4; ++n) {
            int c = 16 * n + l15;
            #pragma unroll
            for (int e = 0; e < 4; ++e)
                if (row + e < M) out[(size_t)(row + e) * COUT + c] = acc[s][n][e];
        }
    }
    // fused BN stats (rows >= M are exact zeros)
    #pragma unroll
    for (int n = 0; n < 4; ++n) {
        float s1 = 0.f, sq = 0.f;
        #pragma unroll
        for (int s = 0; s < 2; ++s)
            #pragma unroll
            for (int e = 0; e < 4; ++e) { float v = acc[s][n][e]; s1 += v; sq += v * v; }
        s1 += __shfl_xor(s1, 16); sq += __shfl_xor(sq, 16);
        s1 += __shfl_xor(s1, 32); sq += __shfl_xor(sq, 32);
        if (quad == 0) {
            atomicAdd(&red_s[16 * n + l15], s1);
            atomicAdd(&red_q[16 * n + l15], sq);
        }
    }
    __syncthreads();
    if (t < 64)       atomicAdd(&red[t], red_s[t]);
    else if (t < 128) atomicAdd(&red[t], red_q[t - 64]);
}

__global__ void finC_kernel(const float* __restrict__ red, const float* __restrict__ g,
                            const float* __restrict__ b, float* __restrict__ scale,
                            float* __restrict__ shift, int M)
{
    int c = threadIdx.x;  // 64
    float m = red[c] / (float)M;
    float var = red[64 + c] / (float)M - m * m;
    float sc = g[c] / sqrtf(var + EPSF);
    scale[c] = sc;
    shift[c] = b[c] - m * sc;
}

// out = elu( elu(scale2*raw + shift2) + down )
__global__ void final_kernel(float* __restrict__ out, const float* __restrict__ down,
                             const float* __restrict__ scale2, const float* __restrict__ shift2,
                             int n)
{
    int i = blockIdx.x * 256 + threadIdx.x;
    if (i < n) {
        int c = i & 63;
        float y = eluf(out[i] * scale2[c] + shift2[c]);
        out[i] = eluf(y + down[i]);
    }
}

extern "C" void kernel_launch(void* const* d_in, const int* in_sizes, int n_in,
                              void* d_out, int out_size, void* d_ws, size_t ws_size,
                              hipStream_t stream)
{
    (void)n_in; (void)ws_size;
    const float* feats    = (const float*)d_in[0];
    const float* Wd       = (const float*)d_in[1];
    const float* g0       = (const float*)d_in[2];
    const float* b0       = (const float*)d_in[3];
    const float* W1       = (const float*)d_in[4];
    const float* g1       = (const float*)d_in[5];
    const float* b1       = (const float*)d_in[6];
    const float* W2       = (const float*)d_in[7];
    const float* g2       = (const float*)d_in[8];
    const float* b2       = (const float*)d_in[9];
    const int*   pool_seg = (const int*)d_in[10];
    const int*   conv_in  = (const int*)d_in[11];
    const int*   conv_out = (const int*)d_in[12];

    int N = in_sizes[0] / CIN;
    int M = out_size / COUT;
    int L = in_sizes[11] / KVOL;

    char* ws = (char*)d_ws;
    size_t off = 0;
    auto alloc = [&](size_t bytes) -> void* {
        void* p = ws + off;
        off = (off + bytes + 255) & ~(size_t)255;
        return p;
    };
    float*          down    = (float*)alloc((size_t)M * COUT * 4);
    float*          o1      = (float*)alloc((size_t)M * COUT * 4);
    unsigned short* down_bf = (unsigned short*)alloc((size_t)M * COUT * 2);
    unsigned short* o1t     = (unsigned short*)alloc((size_t)M * COUT * 2);
    int*            nbrT    = (int*)alloc((size_t)KVOL * M * 4);
    unsigned short* Wt1     = (unsigned short*)alloc((size_t)KVOL * COUT * COUT * 2);
    unsigned short* Wt2     = (unsigned short*)alloc((size_t)KVOL * COUT * COUT * 2);
    int*            cnt     = (int*)alloc((size_t)M * 4);
    int*            bucket  = (int*)alloc((size_t)M * 16 * 4);
    float* red  = (float*)alloc((size_t)(1056 + 128 + 128) * 4);
    float* red0 = red, *red1 = red + 1056, *red2 = red + 1056 + 128;
    float* sreg = (float*)alloc((size_t)6 * 64 * 4);
    float* scale0 = sreg, *shift0 = sreg + 64;
    float* scale1 = sreg + 128, *shift1 = sreg + 192;
    float* scale2 = sreg + 256, *shift2 = sreg + 320;

    hipMemsetAsync(nbrT, 0xFF, (size_t)KVOL * M * 4, stream);       // -1 = missing neighbor
    hipMemsetAsync(cnt, 0, (size_t)M * 4, stream);                  // bucket counters
    hipMemsetAsync(red, 0, (size_t)(1056 + 128 + 128) * 4, stream); // stat accumulators

    feat_moments_kernel<<<1024, 256, 0, stream>>>(feats, red0, N);
    fin0_kernel<<<1, 64, 0, stream>>>(red0, Wd, g0, b0, scale0, shift0, N);
    bucket_kernel<<<(N + 255) / 256, 256, 0, stream>>>(pool_seg, cnt, bucket, N);
    pool_kernel<<<(M + 3) / 4, 256, 0, stream>>>(
        feats, Wd, cnt, bucket, scale0, shift0, down, down_bf, M);
    cvt_w_kernel<<<2 * KVOL, 256, 0, stream>>>(W1, W2, Wt1, Wt2);
    dim3 gn((L + 255) / 256, KVOL);
    nbr_kernel<<<gn, 256, 0, stream>>>(conv_out, conv_in, nbrT, L, M);

    int cblocks = (M + 127) / 128;
    conv_mfma_kernel<<<cblocks, 256, 0, stream>>>(down_bf, Wt1, nbrT, M, o1, red1);
    finC_kernel<<<1, 64, 0, stream>>>(red1, g1, b1, scale1, shift1, M);
    bn_elu_cvt_kernel<<<(M * COUT + 255) / 256, 256, 0, stream>>>(o1, scale1, shift1, o1t, M * COUT);
    conv_mfma_kernel<<<cblocks, 256, 0, stream>>>(o1t, Wt2, nbrT, M, (float*)d_out, red2);
    finC_kernel<<<1, 64, 0, stream>>>(red2, g2, b2, scale2, shift2, M);
    final_kernel<<<(M * COUT + 255) / 256, 256, 0, stream>>>(
        (float*)d_out, down, scale2, shift2, M * COUT);
}

// Round 4
// 623.691 us; speedup vs baseline: 6.1542x; 1.4567x over previous
//
#include <hip/hip_runtime.h>
#include <math.h>

#define CIN  32
#define COUT 64
#define KVOL 27
#define EPSF 1e-5f

typedef __attribute__((ext_vector_type(8))) short          short8;
typedef __attribute__((ext_vector_type(8))) unsigned short u16x8;
typedef __attribute__((ext_vector_type(4))) float          float4v;

__device__ __forceinline__ float eluf(float x) { return x > 0.f ? x : expm1f(x); }

// f32 -> bf16 round-to-nearest-even
__device__ __forceinline__ unsigned short f2bf(float x) {
    unsigned u = __float_as_uint(x);
    unsigned r = (u + 0x7FFFu + ((u >> 16) & 1u)) >> 16;
    return (unsigned short)r;
}
__device__ __forceinline__ float bf2f(unsigned short h) {
    return __uint_as_float(((unsigned)h) << 16);
}

// ---------------------------------------------------------------------------
// Weight prep: W1/W2 [k][i][c] f32 -> Wt [k][c][i] bf16 (B-frags contiguous),
// block 54: Wd [i][c] f32 -> Wdt [c][i] bf16.
// ---------------------------------------------------------------------------
__global__ void cvt_w_kernel(const float* __restrict__ W1, const float* __restrict__ W2,
                             const float* __restrict__ Wd,
                             unsigned short* __restrict__ Wt1, unsigned short* __restrict__ Wt2,
                             unsigned short* __restrict__ Wdt)
{
    int b = blockIdx.x;  // 0..54
    int t = threadIdx.x;
    if (b == 54) {
        for (int e = t; e < CIN * COUT; e += 256) {
            int i = e >> 6, c = e & 63;
            Wdt[c * CIN + i] = f2bf(Wd[e]);
        }
        return;
    }
    const float* W = (b < 27) ? W1 : W2;
    unsigned short* Wt = (b < 27) ? Wt1 : Wt2;
    int k = (b < 27) ? b : b - 27;
    const float* src = W + (size_t)k * (COUT * COUT);
    unsigned short* dst = Wt + (size_t)k * (COUT * COUT);
    for (int e = t; e < COUT * COUT; e += 256) {
        int i = e >> 6, c = e & 63;
        dst[c * COUT + i] = f2bf(src[e]);
    }
}

// ---------------------------------------------------------------------------
// MFMA down-conv: t = feats @ Wd  (N x 32 @ 32 x 64), K=32 = one k-step.
// Writes t_bf (raw, pre-BN) + fused per-channel sum/sumsq -> red0[0..127].
// Pool/BN0/ELU applied later (monotone => commutes with segment max).
// ---------------------------------------------------------------------------
__global__ __launch_bounds__(256) void gemm_t_kernel(
    const float* __restrict__ feats, const unsigned short* __restrict__ Wdt,
    int N, unsigned short* __restrict__ t_bf, float* __restrict__ red0)
{
    __shared__ __align__(16) unsigned short A_lds[128 * 40];  // 10 KB, stride 40
    __shared__ __align__(16) unsigned short W_lds[64 * 40];   //  5 KB
    __shared__ float red_s[64];
    __shared__ float red_q[64];
    int t = threadIdx.x;
    int base = blockIdx.x * 128;
    int w = t >> 6, lane = t & 63, l15 = lane & 15, quad = lane >> 4;

    if (t < 64) { red_s[t] = 0.f; red_q[t] = 0.f; }

    {   // stage A: 2 threads/row, each converts 16 f32 -> 16 bf16
        int ar = t >> 1, ah = t & 1;
        int gj = base + ar;
        u16x8 h0 = {0,0,0,0,0,0,0,0}, h1 = h0;
        if (gj < N) {
            const float4* src = (const float4*)(feats + (size_t)gj * CIN + ah * 16);
            float4 f0 = src[0], f1 = src[1], f2 = src[2], f3 = src[3];
            h0[0]=f2bf(f0.x); h0[1]=f2bf(f0.y); h0[2]=f2bf(f0.z); h0[3]=f2bf(f0.w);
            h0[4]=f2bf(f1.x); h0[5]=f2bf(f1.y); h0[6]=f2bf(f1.z); h0[7]=f2bf(f1.w);
            h1[0]=f2bf(f2.x); h1[1]=f2bf(f2.y); h1[2]=f2bf(f2.z); h1[3]=f2bf(f2.w);
            h1[4]=f2bf(f3.x); h1[5]=f2bf(f3.y); h1[6]=f2bf(f3.z); h1[7]=f2bf(f3.w);
        }
        u16x8* dst = (u16x8*)(A_lds + ar * 40 + ah * 16);
        dst[0] = h0; dst[1] = h1;
    }
    {   // stage Wdt (64 x 32 bf16): thread -> 8 elems
        int c = t >> 2, q = t & 3;
        *(u16x8*)(W_lds + c * 40 + q * 8) = *(const u16x8*)(Wdt + c * CIN + q * 8);
    }
    __syncthreads();

    short8 a0 = *(const short8*)(A_lds + (32 * w + l15) * 40 + quad * 8);
    short8 a1 = *(const short8*)(A_lds + (32 * w + 16 + l15) * 40 + quad * 8);
    float4v acc[2][4];
    #pragma unroll
    for (int n = 0; n < 4; ++n) {
        short8 b = *(const short8*)(W_lds + (16 * n + l15) * 40 + quad * 8);
        acc[0][n] = __builtin_amdgcn_mfma_f32_16x16x32_bf16(
            a0, b, (float4v){0.f,0.f,0.f,0.f}, 0, 0, 0);
        acc[1][n] = __builtin_amdgcn_mfma_f32_16x16x32_bf16(
            a1, b, (float4v){0.f,0.f,0.f,0.f}, 0, 0, 0);
    }

    // store raw t as bf16 (C/D layout: col=lane&15, row=quad*4+reg)
    #pragma unroll
    for (int s = 0; s < 2; ++s) {
        int row0 = base + 32 * w + 16 * s + quad * 4;
        #pragma unroll
        for (int n = 0; n < 4; ++n) {
            int c = 16 * n + l15;
            #pragma unroll
            for (int e = 0; e < 4; ++e)
                if (row0 + e < N) t_bf[(size_t)(row0 + e) * COUT + c] = f2bf(acc[s][n][e]);
        }
    }
    // fused BN0 stats in f32 (rows >= N are exact zeros)
    #pragma unroll
    for (int n = 0; n < 4; ++n) {
        float s1 = 0.f, sq = 0.f;
        #pragma unroll
        for (int s = 0; s < 2; ++s)
            #pragma unroll
            for (int e = 0; e < 4; ++e) { float v = acc[s][n][e]; s1 += v; sq += v * v; }
        s1 += __shfl_xor(s1, 16); sq += __shfl_xor(sq, 16);
        s1 += __shfl_xor(s1, 32); sq += __shfl_xor(sq, 32);
        if (quad == 0) {
            atomicAdd(&red_s[16 * n + l15], s1);
            atomicAdd(&red_q[16 * n + l15], sq);
        }
    }
    __syncthreads();
    if (t < 64)       atomicAdd(&red0[t], red_s[t]);
    else if (t < 128) atomicAdd(&red0[t], red_q[t - 64]);
}

// ---------------------------------------------------------------------------
// Bucket build: pooling cell = 2x2x4 = 16 voxels max -> fixed capacity 16.
// ---------------------------------------------------------------------------
__global__ void bucket_kernel(const int* __restrict__ pool_seg,
                              int* __restrict__ cnt, int* __restrict__ bucket, int N)
{
    int j = blockIdx.x * 256 + threadIdx.x;
    if (j < N) {
        int s = pool_seg[j];
        int pos = atomicAdd(&cnt[s], 1);
        bucket[(size_t)s * 16 + pos] = j;
    }
}

// ---------------------------------------------------------------------------
// Gather-only pool: thread = (segment, 4 channels). max/min over raw t rows,
// then BN0+ELU on the pooled value (monotone per channel; min covers sc<0).
// ---------------------------------------------------------------------------
__global__ __launch_bounds__(256) void pool_max_kernel(
    const unsigned short* __restrict__ t_bf,
    const int* __restrict__ cnt, const int* __restrict__ bucket,
    const float* __restrict__ scale0, const float* __restrict__ shift0,
    unsigned short* __restrict__ down_bf, int M)
{
    int id = blockIdx.x * 256 + threadIdx.x;
    int s = id >> 4, cg = id & 15;
    if (s >= M) return;
    int n = cnt[s];
    const int4* bk4 = (const int4*)(bucket + (size_t)s * 16);
    float4 mx = make_float4(-INFINITY, -INFINITY, -INFINITY, -INFINITY);
    float4 mn = make_float4( INFINITY,  INFINITY,  INFINITY,  INFINITY);
    #pragma unroll
    for (int ch = 0; ch < 4; ++ch) {
        if (ch * 4 >= n) break;
        int4 b4 = bk4[ch];
        #pragma unroll
        for (int e = 0; e < 4; ++e) {
            int p = ch * 4 + e;
            if (p < n) {
                int idx = (e == 0) ? b4.x : (e == 1) ? b4.y : (e == 2) ? b4.z : b4.w;
                ushort4 v = *(const ushort4*)(t_bf + (size_t)idx * COUT + cg * 4);
                float f0 = bf2f(v.x), f1 = bf2f(v.y), f2 = bf2f(v.z), f3 = bf2f(v.w);
                mx.x = fmaxf(mx.x, f0); mn.x = fminf(mn.x, f0);
                mx.y = fmaxf(mx.y, f1); mn.y = fminf(mn.y, f1);
                mx.z = fmaxf(mx.z, f2); mn.z = fminf(mn.z, f2);
                mx.w = fmaxf(mx.w, f3); mn.w = fminf(mn.w, f3);
            }
        }
    }
    int c0 = cg * 4;
    float4 sc = *(const float4*)(scale0 + c0);
    float4 sh = *(const float4*)(shift0 + c0);
    ushort4 o;
    o.x = f2bf(eluf(sc.x * (sc.x >= 0.f ? mx.x : mn.x) + sh.x));
    o.y = f2bf(eluf(sc.y * (sc.y >= 0.f ? mx.y : mn.y) + sh.y));
    o.z = f2bf(eluf(sc.z * (sc.z >= 0.f ? mx.z : mn.z) + sh.z));
    o.w = f2bf(eluf(sc.w * (sc.w >= 0.f ? mx.w : mn.w) + sh.w));
    *(ushort4*)(down_bf + (size_t)s * COUT + c0) = o;
}

// invert (k, pairlist) maps into nbrT[k][M] (transposed for coalesced conv reads)
__global__ void nbr_kernel(const int* __restrict__ conv_out, const int* __restrict__ conv_in,
                           int* __restrict__ nbrT, int L, int M)
{
    int k = blockIdx.y;
    int idx = blockIdx.x * 256 + threadIdx.x;
    if (idx < L) {
        int e = k * L + idx;
        int j = conv_out[e];
        if (j < M) nbrT[(size_t)k * M + j] = conv_in[e];
    }
}

// o1t = bf16( ELU(scale1*o1 + shift1) )  -- conv2's A-matrix
__global__ void bn_elu_cvt_kernel(const float* __restrict__ o1,
                                  const float* __restrict__ scale,
                                  const float* __restrict__ shift,
                                  unsigned short* __restrict__ o1t, int n)
{
    int i = blockIdx.x * 256 + threadIdx.x;
    if (i < n) {
        int c = i & 63;
        o1t[i] = f2bf(eluf(o1[i] * scale[c] + shift[c]));
    }
}

// ---------------------------------------------------------------------------
// MFMA implicit-GEMM sparse conv. Block = 128 rows x 64 cols, 4 waves.
// K-loop: 27 offsets x K=64. Fused BN stats epilogue.
// ---------------------------------------------------------------------------
__global__ __launch_bounds__(256) void conv_mfma_kernel(
    const unsigned short* __restrict__ in, const unsigned short* __restrict__ Wt,
    const int* __restrict__ nbrT, int M,
    float* __restrict__ out, float* __restrict__ red)
{
    __shared__ __align__(16) unsigned short A_lds[128 * 72];  // 18.4 KB
    __shared__ __align__(16) unsigned short W_lds[64 * 72];   //  9.2 KB
    __shared__ float red_s[64];
    __shared__ float red_q[64];
    int t = threadIdx.x;
    int base = blockIdx.x * 128;
    int w = t >> 6, lane = t & 63, l15 = lane & 15, quad = lane >> 4;

    if (t < 64) { red_s[t] = 0.f; red_q[t] = 0.f; }

    float4v acc[2][4];
    #pragma unroll
    for (int s = 0; s < 2; ++s)
        #pragma unroll
        for (int n = 0; n < 4; ++n)
            acc[s][n] = (float4v){0.f, 0.f, 0.f, 0.f};

    int ar = t >> 1, ah = t & 1;   // A staging: row, 64B-half
    int gj = base + ar;
    int wc = t >> 2, wq = t & 3;   // W staging: row, 32B-chunk

    for (int k = 0; k < KVOL; ++k) {
        __syncthreads();
        {   // stage A: gathered rows (2 threads/row, 64 B each)
            int idx = (gj < M) ? nbrT[(size_t)k * M + gj] : -1;
            u16x8 c0 = {0,0,0,0,0,0,0,0}, c1 = c0, c2 = c0, c3 = c0;
            if (idx >= 0) {
                const u16x8* src = (const u16x8*)(in + (size_t)idx * COUT + 32 * ah);
                c0 = src[0]; c1 = src[1]; c2 = src[2]; c3 = src[3];
            }
            u16x8* dst = (u16x8*)(A_lds + ar * 72 + 32 * ah);
            dst[0] = c0; dst[1] = c1; dst[2] = c2; dst[3] = c3;
        }
        {   // stage Wt[k] (8 KB)
            const u16x8* src = (const u16x8*)(Wt + (size_t)k * (COUT * COUT) + wc * COUT + 16 * wq);
            u16x8* dst = (u16x8*)(W_lds + wc * 72 + 16 * wq);
            dst[0] = src[0]; dst[1] = src[1];
        }
        __syncthreads();
        #pragma unroll
        for (int kk = 0; kk < 64; kk += 32) {
            short8 a0 = *(const short8*)(A_lds + (32 * w + l15) * 72 + kk + quad * 8);
            short8 a1 = *(const short8*)(A_lds + (32 * w + 16 + l15) * 72 + kk + quad * 8);
            #pragma unroll
            for (int n = 0; n < 4; ++n) {
                short8 b = *(const short8*)(W_lds + (16 * n + l15) * 72 + kk + quad * 8);
                acc[0][n] = __builtin_amdgcn_mfma_f32_16x16x32_bf16(a0, b, acc[0][n], 0, 0, 0);
                acc[1][n] = __builtin_amdgcn_mfma_f32_16x16x32_bf16(a1, b, acc[1][n], 0, 0, 0);
            }
        }
    }

    // stores (C/D layout: col=lane&15, row=quad*4+reg)
    #pragma unroll
    for (int s = 0; s < 2; ++s) {
        int row = base + 32 * w + 16 * s + quad * 4;
        #pragma unroll
        for (int n = 0; n < 4; ++n) {
            int c = 16 * n + l15;
            #pragma unroll
            for (int e = 0; e < 4; ++e)
                if (row + e < M) out[(size_t)(row + e) * COUT + c] = acc[s][n][e];
        }
    }
    // fused BN stats (rows >= M are exact zeros)
    #pragma unroll
    for (int n = 0; n < 4; ++n) {
        float s1 = 0.f, sq = 0.f;
        #pragma unroll
        for (int s = 0; s < 2; ++s)
            #pragma unroll
            for (int e = 0; e < 4; ++e) { float v = acc[s][n][e]; s1 += v; sq += v * v; }
        s1 += __shfl_xor(s1, 16); sq += __shfl_xor(sq, 16);
        s1 += __shfl_xor(s1, 32); sq += __shfl_xor(sq, 32);
        if (quad == 0) {
            atomicAdd(&red_s[16 * n + l15], s1);
            atomicAdd(&red_q[16 * n + l15], sq);
        }
    }
    __syncthreads();
    if (t < 64)       atomicAdd(&red[t], red_s[t]);
    else if (t < 128) atomicAdd(&red[t], red_q[t - 64]);
}

// BN finalize from sum/sumsq: scale = g/sqrt(var+eps), shift = b - mean*scale
__global__ void finC_kernel(const float* __restrict__ red, const float* __restrict__ g,
                            const float* __restrict__ b, float* __restrict__ scale,
                            float* __restrict__ shift, int M)
{
    int c = threadIdx.x;  // 64
    float m = red[c] / (float)M;
    float var = red[64 + c] / (float)M - m * m;
    float sc = g[c] / sqrtf(var + EPSF);
    scale[c] = sc;
    shift[c] = b[c] - m * sc;
}

// out = elu( elu(scale2*raw + shift2) + down )
__global__ void final_kernel(float* __restrict__ out, const unsigned short* __restrict__ down_bf,
                             const float* __restrict__ scale2, const float* __restrict__ shift2,
                             int n)
{
    int i = blockIdx.x * 256 + threadIdx.x;
    if (i < n) {
        int c = i & 63;
        float y = eluf(out[i] * scale2[c] + shift2[c]);
        out[i] = eluf(y + bf2f(down_bf[i]));
    }
}

extern "C" void kernel_launch(void* const* d_in, const int* in_sizes, int n_in,
                              void* d_out, int out_size, void* d_ws, size_t ws_size,
                              hipStream_t stream)
{
    (void)n_in; (void)ws_size;
    const float* feats    = (const float*)d_in[0];
    const float* Wd       = (const float*)d_in[1];
    const float* g0       = (const float*)d_in[2];
    const float* b0       = (const float*)d_in[3];
    const float* W1       = (const float*)d_in[4];
    const float* g1       = (const float*)d_in[5];
    const float* b1       = (const float*)d_in[6];
    const float* W2       = (const float*)d_in[7];
    const float* g2       = (const float*)d_in[8];
    const float* b2       = (const float*)d_in[9];
    const int*   pool_seg = (const int*)d_in[10];
    const int*   conv_in  = (const int*)d_in[11];
    const int*   conv_out = (const int*)d_in[12];

    int N = in_sizes[0] / CIN;
    int M = out_size / COUT;
    int L = in_sizes[11] / KVOL;

    char* ws = (char*)d_ws;
    size_t off = 0;
    auto alloc = [&](size_t bytes) -> void* {
        void* p = ws + off;
        off = (off + bytes + 255) & ~(size_t)255;
        return p;
    };
    float*          o1      = (float*)alloc((size_t)M * COUT * 4);
    unsigned short* down_bf = (unsigned short*)alloc((size_t)M * COUT * 2);
    unsigned short* o1t     = (unsigned short*)alloc((size_t)M * COUT * 2);
    unsigned short* t_bf    = (unsigned short*)alloc((size_t)N * COUT * 2);
    int*            nbrT    = (int*)alloc((size_t)KVOL * M * 4);
    unsigned short* Wt1     = (unsigned short*)alloc((size_t)KVOL * COUT * COUT * 2);
    unsigned short* Wt2     = (unsigned short*)alloc((size_t)KVOL * COUT * COUT * 2);
    unsigned short* Wdt     = (unsigned short*)alloc((size_t)CIN * COUT * 2);
    int*            cnt     = (int*)alloc((size_t)M * 4);
    int*            bucket  = (int*)alloc((size_t)M * 16 * 4);
    float* red  = (float*)alloc((size_t)384 * 4);
    float* red0 = red, *red1 = red + 128, *red2 = red + 256;
    float* sreg = (float*)alloc((size_t)6 * 64 * 4);
    float* scale0 = sreg, *shift0 = sreg + 64;
    float* scale1 = sreg + 128, *shift1 = sreg + 192;
    float* scale2 = sreg + 256, *shift2 = sreg + 320;

    hipMemsetAsync(nbrT, 0xFF, (size_t)KVOL * M * 4, stream);  // -1 = missing neighbor
    hipMemsetAsync(cnt, 0, (size_t)M * 4, stream);             // bucket counters
    hipMemsetAsync(red, 0, (size_t)384 * 4, stream);           // stat accumulators

    cvt_w_kernel<<<55, 256, 0, stream>>>(W1, W2, Wd, Wt1, Wt2, Wdt);
    gemm_t_kernel<<<(N + 127) / 128, 256, 0, stream>>>(feats, Wdt, N, t_bf, red0);
    finC_kernel<<<1, 64, 0, stream>>>(red0, g0, b0, scale0, shift0, N);
    bucket_kernel<<<(N + 255) / 256, 256, 0, stream>>>(pool_seg, cnt, bucket, N);
    pool_max_kernel<<<(M * 16 + 255) / 256, 256, 0, stream>>>(
        t_bf, cnt, bucket, scale0, shift0, down_bf, M);
    dim3 gn((L + 255) / 256, KVOL);
    nbr_kernel<<<gn, 256, 0, stream>>>(conv_out, conv_in, nbrT, L, M);

    int cblocks = (M + 127) / 128;
    conv_mfma_kernel<<<cblocks, 256, 0, stream>>>(down_bf, Wt1, nbrT, M, o1, red1);
    finC_kernel<<<1, 64, 0, stream>>>(red1, g1, b1, scale1, shift1, M);
    bn_elu_cvt_kernel<<<(M * COUT + 255) / 256, 256, 0, stream>>>(o1, scale1, shift1, o1t, M * COUT);
    conv_mfma_kernel<<<cblocks, 256, 0, stream>>>(o1t, Wt2, nbrT, M, (float*)d_out, red2);
    finC_kernel<<<1, 64, 0, stream>>>(red2, g2, b2, scale2, shift2, M);
    final_kernel<<<(M * COUT + 255) / 256, 256, 0, stream>>>(
        (float*)d_out, down_bf, scale2, shift2, M * COUT);
}

// Round 5
// 550.971 us; speedup vs baseline: 6.9665x; 1.1320x over previous
//
#include <hip/hip_runtime.h>
#include <math.h>

#define CIN  32
#define COUT 64
#define KVOL 27
#define EPSF 1e-5f

typedef __attribute__((ext_vector_type(8))) short          short8;
typedef __attribute__((ext_vector_type(8))) unsigned short u16x8;
typedef __attribute__((ext_vector_type(4))) float          float4v;

__device__ __forceinline__ float eluf(float x) { return x > 0.f ? x : expm1f(x); }

// f32 -> bf16 round-to-nearest-even
__device__ __forceinline__ unsigned short f2bf(float x) {
    unsigned u = __float_as_uint(x);
    unsigned r = (u + 0x7FFFu + ((u >> 16) & 1u)) >> 16;
    return (unsigned short)r;
}
__device__ __forceinline__ unsigned pk2bf(float lo, float hi) {
    return (unsigned)f2bf(lo) | ((unsigned)f2bf(hi) << 16);
}
__device__ __forceinline__ float bf2f(unsigned short h) {
    return __uint_as_float(((unsigned)h) << 16);
}

// ---------------------------------------------------------------------------
// Weight prep: W1/W2 [k][i][c] f32 -> Wt [k][c][i] bf16 (B-frags contiguous),
// block 54: Wd [i][c] f32 -> Wdt [c][i] bf16.
// ---------------------------------------------------------------------------
__global__ void cvt_w_kernel(const float* __restrict__ W1, const float* __restrict__ W2,
                             const float* __restrict__ Wd,
                             unsigned short* __restrict__ Wt1, unsigned short* __restrict__ Wt2,
                             unsigned short* __restrict__ Wdt)
{
    int b = blockIdx.x;  // 0..54
    int t = threadIdx.x;
    if (b == 54) {
        for (int e = t; e < CIN * COUT; e += 256) {
            int i = e >> 6, c = e & 63;
            Wdt[c * CIN + i] = f2bf(Wd[e]);
        }
        return;
    }
    const float* W = (b < 27) ? W1 : W2;
    unsigned short* Wt = (b < 27) ? Wt1 : Wt2;
    int k = (b < 27) ? b : b - 27;
    const float* src = W + (size_t)k * (COUT * COUT);
    unsigned short* dst = Wt + (size_t)k * (COUT * COUT);
    for (int e = t; e < COUT * COUT; e += 256) {
        int i = e >> 6, c = e & 63;
        dst[c * COUT + i] = f2bf(src[e]);
    }
}

// ---------------------------------------------------------------------------
// Transposed streaming down-conv: t^T = Wd^T @ feats^T, zero LDS in hot loop.
// A-operand = Wdt (hoisted, tile-invariant). B-operand = feats loaded straight
// from global (wave covers 16 rows x 128 B contiguous). D: lane holds 4
// consecutive channels of one point -> packed 8 B bf16 stores.
// Persistent grid + register prefetch. Fused BN0 stats (register-accumulated,
// flushed once per block into 4-way-spread red0 to cut atomic contention).
// ---------------------------------------------------------------------------
__global__ __launch_bounds__(256) void gemm_t_kernel(
    const float* __restrict__ feats, const unsigned short* __restrict__ Wdt,
    int N, unsigned short* __restrict__ t_bf, float* __restrict__ red0)
{
    __shared__ float red_s[64];
    __shared__ float red_q[64];
    int t = threadIdx.x;
    if (t < 64) { red_s[t] = 0.f; red_q[t] = 0.f; }
    __syncthreads();

    int w = t >> 6, lane = t & 63, l15 = lane & 15, quad = lane >> 4;

    // hoist A-frags: aw[mt] = Wd^T rows 16mt+l15, k = quad*8..+7
    short8 aw[4];
    #pragma unroll
    for (int mt = 0; mt < 4; ++mt)
        aw[mt] = *(const short8*)(Wdt + (size_t)(16 * mt + l15) * CIN + quad * 8);

    float s1[16], sq[16];
    #pragma unroll
    for (int e = 0; e < 16; ++e) { s1[e] = 0.f; sq[e] = 0.f; }

    int numTiles = (N + 15) >> 4;
    int stride = gridDim.x * 4;
    int tile = blockIdx.x * 4 + w;

    float4 c0 = make_float4(0.f, 0.f, 0.f, 0.f), c1 = c0;
    {
        int pt = tile * 16 + l15;
        if (tile < numTiles && pt < N) {
            const float4* s = (const float4*)(feats + (size_t)pt * CIN + quad * 8);
            c0 = s[0]; c1 = s[1];
        }
    }

    while (tile < numTiles) {
        // prefetch next tile
        int nt = tile + stride;
        float4 n0 = make_float4(0.f, 0.f, 0.f, 0.f), n1 = n0;
        {
            int npt = nt * 16 + l15;
            if (nt < numTiles && npt < N) {
                const float4* s = (const float4*)(feats + (size_t)npt * CIN + quad * 8);
                n0 = s[0]; n1 = s[1];
            }
        }
        // convert current B-frag (feats[pt][quad*8..+7] -> 8 bf16)
        union { short8 v; unsigned u[4]; } b;
        b.u[0] = pk2bf(c0.x, c0.y);
        b.u[1] = pk2bf(c0.z, c0.w);
        b.u[2] = pk2bf(c1.x, c1.y);
        b.u[3] = pk2bf(c1.z, c1.w);

        float4v acc[4];
        #pragma unroll
        for (int mt = 0; mt < 4; ++mt)
            acc[mt] = __builtin_amdgcn_mfma_f32_16x16x32_bf16(
                aw[mt], b.v, (float4v){0.f, 0.f, 0.f, 0.f}, 0, 0, 0);

        int pt = tile * 16 + l15;
        if (pt < N) {
            #pragma unroll
            for (int mt = 0; mt < 4; ++mt) {
                uint2 o;
                o.x = pk2bf(acc[mt][0], acc[mt][1]);
                o.y = pk2bf(acc[mt][2], acc[mt][3]);
                *(uint2*)(t_bf + (size_t)pt * COUT + mt * 16 + quad * 4) = o;
            }
        }
        // stats (padded lanes contribute exact zeros)
        #pragma unroll
        for (int mt = 0; mt < 4; ++mt)
            #pragma unroll
            for (int e = 0; e < 4; ++e) {
                float v = acc[mt][e];
                s1[mt * 4 + e] += v; sq[mt * 4 + e] += v * v;
            }
        c0 = n0; c1 = n1;
        tile = nt;
    }

    // reduce stats: butterfly over the 16 point-lanes, then LDS, then global
    #pragma unroll
    for (int m = 1; m <= 8; m <<= 1) {
        #pragma unroll
        for (int e = 0; e < 16; ++e) {
            s1[e] += __shfl_xor(s1[e], m);
            sq[e] += __shfl_xor(sq[e], m);
        }
    }
    if (l15 == 0) {
        #pragma unroll
        for (int e = 0; e < 16; ++e) {
            int ch = (e >> 2) * 16 + quad * 4 + (e & 3);
            atomicAdd(&red_s[ch], s1[e]);
            atomicAdd(&red_q[ch], sq[e]);
        }
    }
    __syncthreads();
    float* dst = red0 + (size_t)(blockIdx.x & 3) * 128;
    if (t < 64)       atomicAdd(&dst[t], red_s[t]);
    else if (t < 128) atomicAdd(&dst[t], red_q[t - 64]);
}

// BN finalize from 4-way-spread sum/sumsq (for BN0)
__global__ void fin0_kernel(const float* __restrict__ red, const float* __restrict__ g,
                            const float* __restrict__ b, float* __restrict__ scale,
                            float* __restrict__ shift, int cnt)
{
    int c = threadIdx.x;  // 64
    float s = 0.f, q = 0.f;
    #pragma unroll
    for (int i = 0; i < 4; ++i) { s += red[i * 128 + c]; q += red[i * 128 + 64 + c]; }
    float m = s / (float)cnt;
    float var = q / (float)cnt - m * m;
    float sc = g[c] / sqrtf(var + EPSF);
    scale[c] = sc;
    shift[c] = b[c] - m * sc;
}

// ---------------------------------------------------------------------------
// Bucket build: pooling cell = 2x2x4 = 16 voxels max -> fixed capacity 16.
// ---------------------------------------------------------------------------
__global__ void bucket_kernel(const int* __restrict__ pool_seg,
                              int* __restrict__ cnt, int* __restrict__ bucket, int N)
{
    int j = blockIdx.x * 256 + threadIdx.x;
    if (j < N) {
        int s = pool_seg[j];
        int pos = atomicAdd(&cnt[s], 1);
        bucket[(size_t)s * 16 + pos] = j;
    }
}

// ---------------------------------------------------------------------------
// Gather-only pool: thread = (segment, 4 channels). max/min over raw t rows,
// then BN0+ELU on the pooled value (monotone per channel; min covers sc<0).
// ---------------------------------------------------------------------------
__global__ __launch_bounds__(256) void pool_max_kernel(
    const unsigned short* __restrict__ t_bf,
    const int* __restrict__ cnt, const int* __restrict__ bucket,
    const float* __restrict__ scale0, const float* __restrict__ shift0,
    unsigned short* __restrict__ down_bf, int M)
{
    int id = blockIdx.x * 256 + threadIdx.x;
    int s = id >> 4, cg = id & 15;
    if (s >= M) return;
    int n = cnt[s];
    const int4* bk4 = (const int4*)(bucket + (size_t)s * 16);
    float4 mx = make_float4(-INFINITY, -INFINITY, -INFINITY, -INFINITY);
    float4 mn = make_float4( INFINITY,  INFINITY,  INFINITY,  INFINITY);
    #pragma unroll
    for (int ch = 0; ch < 4; ++ch) {
        if (ch * 4 >= n) break;
        int4 b4 = bk4[ch];
        #pragma unroll
        for (int e = 0; e < 4; ++e) {
            int p = ch * 4 + e;
            if (p < n) {
                int idx = (e == 0) ? b4.x : (e == 1) ? b4.y : (e == 2) ? b4.z : b4.w;
                ushort4 v = *(const ushort4*)(t_bf + (size_t)idx * COUT + cg * 4);
                float f0 = bf2f(v.x), f1 = bf2f(v.y), f2 = bf2f(v.z), f3 = bf2f(v.w);
                mx.x = fmaxf(mx.x, f0); mn.x = fminf(mn.x, f0);
                mx.y = fmaxf(mx.y, f1); mn.y = fminf(mn.y, f1);
                mx.z = fmaxf(mx.z, f2); mn.z = fminf(mn.z, f2);
                mx.w = fmaxf(mx.w, f3); mn.w = fminf(mn.w, f3);
            }
        }
    }
    int c0 = cg * 4;
    float4 sc = *(const float4*)(scale0 + c0);
    float4 sh = *(const float4*)(shift0 + c0);
    ushort4 o;
    o.x = f2bf(eluf(sc.x * (sc.x >= 0.f ? mx.x : mn.x) + sh.x));
    o.y = f2bf(eluf(sc.y * (sc.y >= 0.f ? mx.y : mn.y) + sh.y));
    o.z = f2bf(eluf(sc.z * (sc.z >= 0.f ? mx.z : mn.z) + sh.z));
    o.w = f2bf(eluf(sc.w * (sc.w >= 0.f ? mx.w : mn.w) + sh.w));
    *(ushort4*)(down_bf + (size_t)s * COUT + c0) = o;
}

// invert (k, pairlist) maps into nbrT[k][M] (transposed for coalesced conv reads)
__global__ void nbr_kernel(const int* __restrict__ conv_out, const int* __restrict__ conv_in,
                           int* __restrict__ nbrT, int L, int M)
{
    int k = blockIdx.y;
    int idx = blockIdx.x * 256 + threadIdx.x;
    if (idx < L) {
        int e = k * L + idx;
        int j = conv_out[e];
        if (j < M) nbrT[(size_t)k * M + j] = conv_in[e];
    }
}

// o1t = bf16( ELU(scale1*o1 + shift1) )  -- conv2's A-matrix
__global__ void bn_elu_cvt_kernel(const float* __restrict__ o1,
                                  const float* __restrict__ scale,
                                  const float* __restrict__ shift,
                                  unsigned short* __restrict__ o1t, int n)
{
    int i = blockIdx.x * 256 + threadIdx.x;
    if (i < n) {
        int c = i & 63;
        o1t[i] = f2bf(eluf(o1[i] * scale[c] + shift[c]));
    }
}

// ---------------------------------------------------------------------------
// MFMA implicit-GEMM sparse conv. Block = 128 rows x 64 cols, 4 waves.
// K-loop: 27 offsets x K=64. Fused BN stats epilogue.
// ---------------------------------------------------------------------------
__global__ __launch_bounds__(256) void conv_mfma_kernel(
    const unsigned short* __restrict__ in, const unsigned short* __restrict__ Wt,
    const int* __restrict__ nbrT, int M,
    float* __restrict__ out, float* __restrict__ red)
{
    __shared__ __align__(16) unsigned short A_lds[128 * 72];  // 18.4 KB
    __shared__ __align__(16) unsigned short W_lds[64 * 72];   //  9.2 KB
    __shared__ float red_s[64];
    __shared__ float red_q[64];
    int t = threadIdx.x;
    int base = blockIdx.x * 128;
    int w = t >> 6, lane = t & 63, l15 = lane & 15, quad = lane >> 4;

    if (t < 64) { red_s[t] = 0.f; red_q[t] = 0.f; }

    float4v acc[2][4];
    #pragma unroll
    for (int s = 0; s < 2; ++s)
        #pragma unroll
        for (int n = 0; n < 4; ++n)
            acc[s][n] = (float4v){0.f, 0.f, 0.f, 0.f};

    int ar = t >> 1, ah = t & 1;   // A staging: row, 64B-half
    int gj = base + ar;
    int wc = t >> 2, wq = t & 3;   // W staging: row, 32B-chunk

    for (int k = 0; k < KVOL; ++k) {
        __syncthreads();
        {   // stage A: gathered rows (2 threads/row, 64 B each)
            int idx = (gj < M) ? nbrT[(size_t)k * M + gj] : -1;
            u16x8 c0 = {0,0,0,0,0,0,0,0}, c1 = c0, c2 = c0, c3 = c0;
            if (idx >= 0) {
                const u16x8* src = (const u16x8*)(in + (size_t)idx * COUT + 32 * ah);
                c0 = src[0]; c1 = src[1]; c2 = src[2]; c3 = src[3];
            }
            u16x8* dst = (u16x8*)(A_lds + ar * 72 + 32 * ah);
            dst[0] = c0; dst[1] = c1; dst[2] = c2; dst[3] = c3;
        }
        {   // stage Wt[k] (8 KB)
            const u16x8* src = (const u16x8*)(Wt + (size_t)k * (COUT * COUT) + wc * COUT + 16 * wq);
            u16x8* dst = (u16x8*)(W_lds + wc * 72 + 16 * wq);
            dst[0] = src[0]; dst[1] = src[1];
        }
        __syncthreads();
        #pragma unroll
        for (int kk = 0; kk < 64; kk += 32) {
            short8 a0 = *(const short8*)(A_lds + (32 * w + l15) * 72 + kk + quad * 8);
            short8 a1 = *(const short8*)(A_lds + (32 * w + 16 + l15) * 72 + kk + quad * 8);
            #pragma unroll
            for (int n = 0; n < 4; ++n) {
                short8 b = *(const short8*)(W_lds + (16 * n + l15) * 72 + kk + quad * 8);
                acc[0][n] = __builtin_amdgcn_mfma_f32_16x16x32_bf16(a0, b, acc[0][n], 0, 0, 0);
                acc[1][n] = __builtin_amdgcn_mfma_f32_16x16x32_bf16(a1, b, acc[1][n], 0, 0, 0);
            }
        }
    }

    // stores (C/D layout: col=lane&15, row=quad*4+reg)
    #pragma unroll
    for (int s = 0; s < 2; ++s) {
        int row = base + 32 * w + 16 * s + quad * 4;
        #pragma unroll
        for (int n = 0; n < 4; ++n) {
            int c = 16 * n + l15;
            #pragma unroll
            for (int e = 0; e < 4; ++e)
                if (row + e < M) out[(size_t)(row + e) * COUT + c] = acc[s][n][e];
        }
    }
    // fused BN stats (rows >= M are exact zeros)
    #pragma unroll
    for (int n = 0; n < 4; ++n) {
        float s1 = 0.f, sq = 0.f;
        #pragma unroll
        for (int s = 0; s < 2; ++s)
            #pragma unroll
            for (int e = 0; e < 4; ++e) { float v = acc[s][n][e]; s1 += v; sq += v * v; }
        s1 += __shfl_xor(s1, 16); sq += __shfl_xor(sq, 16);
        s1 += __shfl_xor(s1, 32); sq += __shfl_xor(sq, 32);
        if (quad == 0) {
            atomicAdd(&red_s[16 * n + l15], s1);
            atomicAdd(&red_q[16 * n + l15], sq);
        }
    }
    __syncthreads();
    if (t < 64)       atomicAdd(&red[t], red_s[t]);
    else if (t < 128) atomicAdd(&red[t], red_q[t - 64]);
}

// BN finalize from sum/sumsq: scale = g/sqrt(var+eps), shift = b - mean*scale
__global__ void finC_kernel(const float* __restrict__ red, const float* __restrict__ g,
                            const float* __restrict__ b, float* __restrict__ scale,
                            float* __restrict__ shift, int M)
{
    int c = threadIdx.x;  // 64
    float m = red[c] / (float)M;
    float var = red[64 + c] / (float)M - m * m;
    float sc = g[c] / sqrtf(var + EPSF);
    scale[c] = sc;
    shift[c] = b[c] - m * sc;
}

// out = elu( elu(scale2*raw + shift2) + down )
__global__ void final_kernel(float* __restrict__ out, const unsigned short* __restrict__ down_bf,
                             const float* __restrict__ scale2, const float* __restrict__ shift2,
                             int n)
{
    int i = blockIdx.x * 256 + threadIdx.x;
    if (i < n) {
        int c = i & 63;
        float y = eluf(out[i] * scale2[c] + shift2[c]);
        out[i] = eluf(y + bf2f(down_bf[i]));
    }
}

extern "C" void kernel_launch(void* const* d_in, const int* in_sizes, int n_in,
                              void* d_out, int out_size, void* d_ws, size_t ws_size,
                              hipStream_t stream)
{
    (void)n_in; (void)ws_size;
    const float* feats    = (const float*)d_in[0];
    const float* Wd       = (const float*)d_in[1];
    const float* g0       = (const float*)d_in[2];
    const float* b0       = (const float*)d_in[3];
    const float* W1       = (const float*)d_in[4];
    const float* g1       = (const float*)d_in[5];
    const float* b1       = (const float*)d_in[6];
    const float* W2       = (const float*)d_in[7];
    const float* g2       = (const float*)d_in[8];
    const float* b2       = (const float*)d_in[9];
    const int*   pool_seg = (const int*)d_in[10];
    const int*   conv_in  = (const int*)d_in[11];
    const int*   conv_out = (const int*)d_in[12];

    int N = in_sizes[0] / CIN;
    int M = out_size / COUT;
    int L = in_sizes[11] / KVOL;

    char* ws = (char*)d_ws;
    size_t off = 0;
    auto alloc = [&](size_t bytes) -> void* {
        void* p = ws + off;
        off = (off + bytes + 255) & ~(size_t)255;
        return p;
    };
    float*          o1      = (float*)alloc((size_t)M * COUT * 4);
    unsigned short* down_bf = (unsigned short*)alloc((size_t)M * COUT * 2);
    unsigned short* o1t     = (unsigned short*)alloc((size_t)M * COUT * 2);
    unsigned short* t_bf    = (unsigned short*)alloc((size_t)N * COUT * 2);
    int*            nbrT    = (int*)alloc((size_t)KVOL * M * 4);
    unsigned short* Wt1     = (unsigned short*)alloc((size_t)KVOL * COUT * COUT * 2);
    unsigned short* Wt2     = (unsigned short*)alloc((size_t)KVOL * COUT * COUT * 2);
    unsigned short* Wdt     = (unsigned short*)alloc((size_t)CIN * COUT * 2);
    int*            cnt     = (int*)alloc((size_t)M * 4);
    int*            bucket  = (int*)alloc((size_t)M * 16 * 4);
    float* red  = (float*)alloc((size_t)768 * 4);
    float* red0 = red, *red1 = red + 512, *red2 = red + 640;
    float* sreg = (float*)alloc((size_t)6 * 64 * 4);
    float* scale0 = sreg, *shift0 = sreg + 64;
    float* scale1 = sreg + 128, *shift1 = sreg + 192;
    float* scale2 = sreg + 256, *shift2 = sreg + 320;

    hipMemsetAsync(nbrT, 0xFF, (size_t)KVOL * M * 4, stream);  // -1 = missing neighbor
    hipMemsetAsync(cnt, 0, (size_t)M * 4, stream);             // bucket counters
    hipMemsetAsync(red, 0, (size_t)768 * 4, stream);           // stat accumulators

    cvt_w_kernel<<<55, 256, 0, stream>>>(W1, W2, Wd, Wt1, Wt2, Wdt);
    gemm_t_kernel<<<1024, 256, 0, stream>>>(feats, Wdt, N, t_bf, red0);
    fin0_kernel<<<1, 64, 0, stream>>>(red0, g0, b0, scale0, shift0, N);
    bucket_kernel<<<(N + 255) / 256, 256, 0, stream>>>(pool_seg, cnt, bucket, N);
    pool_max_kernel<<<(M * 16 + 255) / 256, 256, 0, stream>>>(
        t_bf, cnt, bucket, scale0, shift0, down_bf, M);
    dim3 gn((L + 255) / 256, KVOL);
    nbr_kernel<<<gn, 256, 0, stream>>>(conv_out, conv_in, nbrT, L, M);

    int cblocks = (M + 127) / 128;
    conv_mfma_kernel<<<cblocks, 256, 0, stream>>>(down_bf, Wt1, nbrT, M, o1, red1);
    finC_kernel<<<1, 64, 0, stream>>>(red1, g1, b1, scale1, shift1, M);
    bn_elu_cvt_kernel<<<(M * COUT + 255) / 256, 256, 0, stream>>>(o1, scale1, shift1, o1t, M * COUT);
    conv_mfma_kernel<<<cblocks, 256, 0, stream>>>(o1t, Wt2, nbrT, M, (float*)d_out, red2);
    finC_kernel<<<1, 64, 0, stream>>>(red2, g2, b2, scale2, shift2, M);
    final_kernel<<<(M * COUT + 255) / 256, 256, 0, stream>>>(
        (float*)d_out, down_bf, scale2, shift2, M * COUT);
}